// Round 15
// baseline (42.129 us; speedup 1.0000x reference)
//
#include <hip/hip_runtime.h>

// DIAGNOSTIC ROUND (R15): R13's kernel with the main compute repeated
// REPS=4x (opaque per-rep offset defeats hoisting; light accumulated and
// scaled by 0.25 -> output exact, nothing DCE-able). Purpose: (1) push the
// kernel above the 39us harness fills so rocprof top-5 shows ITS counters;
// (2) dur(4x)-dur(1x) = 3*M isolates the marginal main-loop cost from the
// prologue+fixed floor. Math identical to R13 (passed, absmax 0.0078).

constexpr int HW     = 512 * 512;
constexpr int WAVES  = 4;
constexpr int GROUPS = 16;    // 256 px per wave
constexpr int REPS   = 4;     // diagnostic multiplier

typedef _Float16 half2v __attribute__((ext_vector_type(2)));
typedef _Float16 half8  __attribute__((ext_vector_type(8)));
typedef float    f32x4  __attribute__((ext_vector_type(4)));

// sin/cos((e+1)*pi/16), e = 0..7  (i = e+1)
__device__ constexpr float SPc[8] = {
    0.195090322f, 0.382683432f, 0.555570233f, 0.707106781f,
    0.831469612f, 0.923879533f, 0.980785280f, 1.0f };
__device__ constexpr float CPc[8] = {
    0.980785280f, 0.923879533f, 0.831469612f, 0.707106781f,
    0.555570233f, 0.382683432f, 0.195090322f, 0.0f };
// sin(j*pi/16), j = 0..31  (cos(j*pi/16) = STc[(j+8)&31])
__device__ constexpr float STc[32] = {
    0.0f,          0.195090322f,  0.382683432f,  0.555570233f,
    0.707106781f,  0.831469612f,  0.923879533f,  0.980785280f,
    1.0f,          0.980785280f,  0.923879533f,  0.831469612f,
    0.707106781f,  0.555570233f,  0.382683432f,  0.195090322f,
    0.0f,         -0.195090322f, -0.382683432f, -0.555570233f,
   -0.707106781f, -0.831469612f, -0.923879533f, -0.980785280f,
   -1.0f,         -0.980785280f, -0.923879533f, -0.831469612f,
   -0.707106781f, -0.555570233f, -0.382683432f, -0.195090322f };

union h8u { unsigned u[4]; half8 v; half2v h2[4]; };

__global__ __launch_bounds__(256, 4)
void env_render_probe(const float* __restrict__ env,
                      const float* __restrict__ normal,
                      const float* __restrict__ albedo,
                      float* __restrict__ out)
{
    __shared__ float lds_env[16 * 32 * 3];        // 6 KB
    __shared__ half8 lds_hf[512];                 // 8 KB
    __shared__ float lds_nrm[WAVES][768];         // 12 KB
    __shared__ float lds_light[WAVES][768];       // 12 KB, [c][256] per wave
    __shared__ float Wred[WAVES][9];

    const int b    = blockIdx.y;
    const int t    = threadIdx.x;
    const int lane = t & 63, wave = t >> 6;
    const int ch   = lane & 15, cg = lane >> 4;

    const int wavepx0 = (blockIdx.x * WAVES + wave) * (GROUPS * 16);

    // ---- Stage env (coalesced) ----
    #pragma unroll
    for (int q = 0; q < 6; ++q)
        lds_env[t + q * 256] = env[(size_t)b * 1536 + t + q * 256];

    // ---- Stage this wave's 768 contiguous normal floats ----
    {
        const float* nsrc = normal + ((size_t)b * HW + wavepx0) * 3;
        #pragma unroll
        for (int q = 0; q < 3; ++q) {
            const f32x4 v = *(const f32x4*)(nsrc + q * 256 + lane * 4);
            *(f32x4*)&lds_nrm[wave][q * 256 + lane * 4] = v;
        }
    }
    // ---- Zero light accumulator (same-wave region) ----
    #pragma unroll
    for (int q = 0; q < 12; ++q) lds_light[wave][q * 64 + lane] = 0.0f;
    __syncthreads();   // env ready

    // ---- Build H^T fragment table ----
    #pragma unroll
    for (int ss = 0; ss < 2; ++ss) {
        const int s = t + ss * 256;
        const int tile = s >> 6, ln = s & 63;
        const int kc = ln >> 4, chh = ln & 15;
        const int j  = tile * 4 + kc;
        half8 f;
        #pragma unroll
        for (int e = 0; e < 8; ++e) {
            const int i = e + 1;
            float v = 0.f;
            if (chh < 3 && !(i == 8 && j >= 16)) {
                const int i2 = 16 - i, j2 = (j + 16) & 31;
                v = (lds_env[(i * 32 + j) * 3 + chh] +
                     lds_env[(i2 * 32 + j2) * 3 + chh]) * (SPc[e] * 0.01f);
            }
            f[e] = (_Float16)v;                   // RNE
        }
        lds_hf[s] = f;
    }

    // ---- W (fp32 exact, 240 pairs) ----
    float W[9];
    #pragma unroll
    for (int q = 0; q < 9; ++q) W[q] = 0.0f;
    if (t < 240) {
        int i, j;
        if (t < 224) { i = 1 + (t >> 5); j = t & 31; }
        else         { i = 8;            j = t - 224; }
        const int i2 = 16 - i, j2 = (j + 16) & 31;
        const float sp = SPc[i - 1], cp = CPc[i - 1];
        const float st = STc[j], ct = STc[(j + 8) & 31];
        const float dx = st * sp, dy = cp, dz = -ct * sp;
        const float scale = sp * 0.01f;
        const float* ea = lds_env + (i * 32 + j) * 3;
        const float* eb = lds_env + (i2 * 32 + j2) * 3;
        const float hd0 = (ea[0] - eb[0]) * scale;
        const float hd1 = (ea[1] - eb[1]) * scale;
        const float hd2 = (ea[2] - eb[2]) * scale;
        W[0] = dx * hd0; W[1] = dx * hd1; W[2] = dx * hd2;
        W[3] = dy * hd0; W[4] = dy * hd1; W[5] = dy * hd2;
        W[6] = dz * hd0; W[7] = dz * hd1; W[8] = dz * hd2;
    }
    #pragma unroll
    for (int q = 0; q < 9; ++q) {
        float v = W[q];
        #pragma unroll
        for (int off = 32; off > 0; off >>= 1) v += __shfl_down(v, off);
        if (lane == 0) Wred[wave][q] = v;
    }
    __syncthreads();

    float Wl[9];
    #pragma unroll
    for (int q = 0; q < 9; ++q)
        Wl[q] = Wred[0][q] + Wred[1][q] + Wred[2][q] + Wred[3][q];

    // ---- Wave invariants ----
    half8 Hf[8];
    #pragma unroll
    for (int tl = 0; tl < 8; ++tl) Hf[tl] = lds_hf[tl * 64 + lane];

    half2v st2[4], ct2[4], sp2[4], cp2[4];
    #pragma unroll
    for (int p = 0; p < 4; ++p) {
        const int ja = (2 * p) * 4 + cg, jb = (2 * p + 1) * 4 + cg;
        st2[p] = half2v{(_Float16)STc[ja], (_Float16)STc[jb]};
        ct2[p] = half2v{(_Float16)STc[(ja + 8) & 31], (_Float16)STc[(jb + 8) & 31]};
        sp2[p] = half2v{(_Float16)SPc[2 * p], (_Float16)SPc[2 * p + 1]};
        cp2[p] = half2v{(_Float16)CPc[2 * p], (_Float16)CPc[2 * p + 1]};
    }

    // ---- Main compute, repeated REPS times (diagnostic) ----
    #pragma unroll 1
    for (int rep = 0; rep < REPS; ++rep) {
        int zoff;                                    // opaque 0: blocks LICM/CSE
        asm volatile("v_mov_b32 %0, 0" : "=v"(zoff));

        #pragma unroll
        for (int g = 0; g < GROUPS; ++g) {
            const int pxl = g * 16 + ch + zoff;          // == g*16+ch at runtime
            const float n0 = lds_nrm[wave][pxl * 3 + 0]; // conflict-free bcast
            const float n1 = lds_nrm[wave][pxl * 3 + 1];
            const float n2 = lds_nrm[wave][pxl * 3 + 2];
            const float nx = fmaf(n2, 2.0f, -1.0f);
            const float ny = fmaf(n1, 2.0f, -1.0f);
            const float nz = fmaf(n0, 2.0f, -1.0f);

            const _Float16 nxh = (_Float16)nx, nyh = (_Float16)ny, nzh = (_Float16)nz;
            const half2v nx2 = {nxh, nxh}, ny2 = {nyh, nyh}, nz2 = {nzh, nzh};

            half2v u2[4], nyc2[4];
            #pragma unroll
            for (int p = 0; p < 4; ++p) {
                u2[p]   = nx2 * st2[p] - nz2 * ct2[p];
                nyc2[p] = ny2 * cp2[p];
            }

            f32x4 acc = {0.f, 0.f, 0.f, 0.f};
            #pragma unroll
            for (int tl = 0; tl < 8; ++tl) {
                const _Float16 uh = (tl & 1) ? u2[tl >> 1].y : u2[tl >> 1].x;
                const half2v ub = {uh, uh};
                h8u pk;
                #pragma unroll
                for (int p = 0; p < 4; ++p) {
                    const half2v d2 = sp2[p] * ub + nyc2[p];   // v_pk_fma_f16
                    pk.h2[p] = d2;
                    pk.u[p] &= 0x7FFF7FFFu;                    // packed |.|
                }
                acc = __builtin_amdgcn_mfma_f32_16x16x32_f16(Hf[tl], pk.v, acc, 0, 0, 0);
            }

            if (cg == 0) {   // accumulate across reps (exact: 4*v*0.25 = v)
                lds_light[wave][pxl]       += acc[0] + fmaf(nx, Wl[0], fmaf(ny, Wl[3], nz * Wl[6]));
                lds_light[wave][256 + pxl] += acc[1] + fmaf(nx, Wl[1], fmaf(ny, Wl[4], nz * Wl[7]));
                lds_light[wave][512 + pxl] += acc[2] + fmaf(nx, Wl[2], fmaf(ny, Wl[5], nz * Wl[8]));
            }
        }
    }
    __syncthreads();

    // ---- Epilogue: coalesced dwordx4, scale by 1/REPS (exact) ----
    const float inv = 1.0f / (float)REPS;   // 0.25, power of two
    const size_t bbase = (size_t)b * 3 * HW + wavepx0;
    #pragma unroll
    for (int c = 0; c < 3; ++c) {
        const f32x4 av = *(const f32x4*)(albedo + bbase + (size_t)c * HW + lane * 4);
        const f32x4 lv = *(const f32x4*)&lds_light[wave][c * 256 + lane * 4];
        f32x4 ov;
        #pragma unroll
        for (int k = 0; k < 4; ++k) ov[k] = av[k] * lv[k] * inv;
        *(f32x4*)(out + bbase + (size_t)c * HW + lane * 4) = ov;
    }
}

extern "C" void kernel_launch(void* const* d_in, const int* in_sizes, int n_in,
                              void* d_out, int out_size, void* d_ws, size_t ws_size,
                              hipStream_t stream)
{
    const float* env    = (const float*)d_in[0];
    const float* normal = (const float*)d_in[1];
    const float* albedo = (const float*)d_in[2];
    float* out          = (float*)d_out;

    const int B = in_sizes[0] / (16 * 32 * 3);               // = 2

    dim3 grid(HW / (WAVES * GROUPS * 16), B);                // (256, B)
    env_render_probe<<<grid, 256, 0, stream>>>(env, normal, albedo, out);
}

// Round 16
// 17.889 us; speedup vs baseline: 2.3550x; 2.3550x over previous
//
#include <hip/hip_runtime.h>

// out[b,c,y,x] = (1/50)*albedo * sum_m relu(n.l_m)*env*sin(phi_i)
// Antipodal pairing (i,j)<->(16-i,(j+16)&31):
//   light = n.W + sum_{256 slots} |n.l_s| * hs_s  (invalid slots hs=0;
//   0.5/50 folded into hs and W).  Factorized dot:
//   d(i,j) = sp_i*(nx*st_j - nz*ct_j) + ny*cp_i;  ct_j = STc[(j+8)&31].
// MFMA: O^T(3 x 16px) += H^T(3 x 256) * P(256 x 16), 8x 16x16x32_f16;
// P in packed fp16 (v_pk_fma_f16 RNE, abs via 0x7FFF mask) = B operand.
// R16 (from R15 probe: M=7.8us/rep, fixed=10.9us, VALUBusy 50% @ 2 w/SIMD):
// GROUPS 16->8 doubles grid to 1024 blocks = 4 blocks/CU = 4 waves/SIMD
// (hides the 50% VALU stall + overlaps prologue chains);
// launch_bounds(256,4) keeps VGPR cap at 64 >= 52 measured (R14's (256,8)
// forced <=32 -> spills -- that's why it didn't help).

constexpr int HW     = 512 * 512;
constexpr int WAVES  = 4;
constexpr int GROUPS = 8;     // 128 px per wave, 512 px per block

typedef _Float16 half2v __attribute__((ext_vector_type(2)));
typedef _Float16 half8  __attribute__((ext_vector_type(8)));
typedef float    f32x4  __attribute__((ext_vector_type(4)));

// sin/cos((e+1)*pi/16), e = 0..7  (i = e+1)
__device__ constexpr float SPc[8] = {
    0.195090322f, 0.382683432f, 0.555570233f, 0.707106781f,
    0.831469612f, 0.923879533f, 0.980785280f, 1.0f };
__device__ constexpr float CPc[8] = {
    0.980785280f, 0.923879533f, 0.831469612f, 0.707106781f,
    0.555570233f, 0.382683432f, 0.195090322f, 0.0f };
// sin(j*pi/16), j = 0..31  (cos(j*pi/16) = STc[(j+8)&31])
__device__ constexpr float STc[32] = {
    0.0f,          0.195090322f,  0.382683432f,  0.555570233f,
    0.707106781f,  0.831469612f,  0.923879533f,  0.980785280f,
    1.0f,          0.980785280f,  0.923879533f,  0.831469612f,
    0.707106781f,  0.555570233f,  0.382683432f,  0.195090322f,
    0.0f,         -0.195090322f, -0.382683432f, -0.555570233f,
   -0.707106781f, -0.831469612f, -0.923879533f, -0.980785280f,
   -1.0f,         -0.980785280f, -0.923879533f, -0.831469612f,
   -0.707106781f, -0.555570233f, -0.382683432f, -0.195090322f };

union h8u { unsigned u[4]; half8 v; half2v h2[4]; };

__global__ __launch_bounds__(256, 4)
void env_render_fused(const float* __restrict__ env,
                      const float* __restrict__ normal,
                      const float* __restrict__ albedo,
                      float* __restrict__ out)
{
    __shared__ float lds_env[16 * 32 * 3];        // 6 KB
    __shared__ half8 lds_hf[512];                 // 8 KB
    __shared__ float lds_nrm[WAVES][GROUPS * 48];   // 6 KB (384 floats/wave)
    __shared__ float lds_light[WAVES][GROUPS * 48]; // 6 KB [c][128] per wave
    __shared__ float Wred[WAVES][9];

    const int b    = blockIdx.y;
    const int t    = threadIdx.x;
    const int lane = t & 63, wave = t >> 6;
    const int ch   = lane & 15, cg = lane >> 4;

    const int wavepx0 = (blockIdx.x * WAVES + wave) * (GROUPS * 16);

    // ---- Stage env (coalesced) ----
    #pragma unroll
    for (int q = 0; q < 6; ++q)
        lds_env[t + q * 256] = env[(size_t)b * 1536 + t + q * 256];

    // ---- Stage this wave's 384 contiguous normal floats (dwordx4 + dx2) ----
    {
        const float* nsrc = normal + ((size_t)b * HW + wavepx0) * 3;
        const f32x4 v = *(const f32x4*)(nsrc + lane * 4);
        *(f32x4*)&lds_nrm[wave][lane * 4] = v;
        const float2 w = *(const float2*)(nsrc + 256 + lane * 2);
        *(float2*)&lds_nrm[wave][256 + lane * 2] = w;
    }
    __syncthreads();   // env ready

    // ---- Build H^T fragment table (2 slots/thread); fp32 math, RNE cvt ----
    #pragma unroll
    for (int ss = 0; ss < 2; ++ss) {
        const int s = t + ss * 256;
        const int tile = s >> 6, ln = s & 63;
        const int kc = ln >> 4, chh = ln & 15;
        const int j  = tile * 4 + kc;
        half8 f;
        #pragma unroll
        for (int e = 0; e < 8; ++e) {
            const int i = e + 1;
            float v = 0.f;
            if (chh < 3 && !(i == 8 && j >= 16)) {
                const int i2 = 16 - i, j2 = (j + 16) & 31;
                v = (lds_env[(i * 32 + j) * 3 + chh] +
                     lds_env[(i2 * 32 + j2) * 3 + chh]) * (SPc[e] * 0.01f);
            }
            f[e] = (_Float16)v;                   // RNE
        }
        lds_hf[s] = f;
    }

    // ---- W = sum_pairs l_a (h_a - h_b)^T  (fp32 exact, 240 pairs) ----
    float W[9];
    #pragma unroll
    for (int q = 0; q < 9; ++q) W[q] = 0.0f;
    if (t < 240) {
        int i, j;
        if (t < 224) { i = 1 + (t >> 5); j = t & 31; }
        else         { i = 8;            j = t - 224; }
        const int i2 = 16 - i, j2 = (j + 16) & 31;
        const float sp = SPc[i - 1], cp = CPc[i - 1];
        const float st = STc[j], ct = STc[(j + 8) & 31];
        const float dx = st * sp, dy = cp, dz = -ct * sp;   // |l| = 1
        const float scale = sp * 0.01f;
        const float* ea = lds_env + (i * 32 + j) * 3;
        const float* eb = lds_env + (i2 * 32 + j2) * 3;
        const float hd0 = (ea[0] - eb[0]) * scale;
        const float hd1 = (ea[1] - eb[1]) * scale;
        const float hd2 = (ea[2] - eb[2]) * scale;
        W[0] = dx * hd0; W[1] = dx * hd1; W[2] = dx * hd2;
        W[3] = dy * hd0; W[4] = dy * hd1; W[5] = dy * hd2;
        W[6] = dz * hd0; W[7] = dz * hd1; W[8] = dz * hd2;
    }
    #pragma unroll
    for (int q = 0; q < 9; ++q) {
        float v = W[q];
        #pragma unroll
        for (int off = 32; off > 0; off >>= 1) v += __shfl_down(v, off);
        if (lane == 0) Wred[wave][q] = v;
    }
    __syncthreads();   // hf + Wred ready

    float Wl[9];
    #pragma unroll
    for (int q = 0; q < 9; ++q)
        Wl[q] = Wred[0][q] + Wred[1][q] + Wred[2][q] + Wred[3][q];

    // ---- Wave invariants ----
    half8 Hf[8];
    #pragma unroll
    for (int tl = 0; tl < 8; ++tl) Hf[tl] = lds_hf[tl * 64 + lane];

    half2v st2[4], ct2[4], sp2[4], cp2[4];
    #pragma unroll
    for (int p = 0; p < 4; ++p) {
        const int ja = (2 * p) * 4 + cg, jb = (2 * p + 1) * 4 + cg;
        st2[p] = half2v{(_Float16)STc[ja], (_Float16)STc[jb]};
        ct2[p] = half2v{(_Float16)STc[(ja + 8) & 31], (_Float16)STc[(jb + 8) & 31]};
        sp2[p] = half2v{(_Float16)SPc[2 * p], (_Float16)SPc[2 * p + 1]};
        cp2[p] = half2v{(_Float16)CPc[2 * p], (_Float16)CPc[2 * p + 1]};
    }

    // ---- Main compute: 8 groups ----
    #pragma unroll
    for (int g = 0; g < GROUPS; ++g) {
        const int pxl = g * 16 + ch;                  // 0..127
        const float n0 = lds_nrm[wave][pxl * 3 + 0];  // conflict-free, cg-bcast
        const float n1 = lds_nrm[wave][pxl * 3 + 1];
        const float n2 = lds_nrm[wave][pxl * 3 + 2];
        const float nx = fmaf(n2, 2.0f, -1.0f);       // flip + decode
        const float ny = fmaf(n1, 2.0f, -1.0f);
        const float nz = fmaf(n0, 2.0f, -1.0f);

        const _Float16 nxh = (_Float16)nx, nyh = (_Float16)ny, nzh = (_Float16)nz;
        const half2v nx2 = {nxh, nxh}, ny2 = {nyh, nyh}, nz2 = {nzh, nzh};

        half2v u2[4], nyc2[4];
        #pragma unroll
        for (int p = 0; p < 4; ++p) {
            u2[p]   = nx2 * st2[p] - nz2 * ct2[p];    // v_pk ops
            nyc2[p] = ny2 * cp2[p];
        }

        f32x4 acc = {0.f, 0.f, 0.f, 0.f};
        #pragma unroll
        for (int tl = 0; tl < 8; ++tl) {
            const _Float16 uh = (tl & 1) ? u2[tl >> 1].y : u2[tl >> 1].x;
            const half2v ub = {uh, uh};
            h8u pk;
            #pragma unroll
            for (int p = 0; p < 4; ++p) {
                const half2v d2 = sp2[p] * ub + nyc2[p];   // v_pk_fma_f16 RNE
                pk.h2[p] = d2;
                pk.u[p] &= 0x7FFF7FFFu;                    // packed |.|
            }
            acc = __builtin_amdgcn_mfma_f32_16x16x32_f16(Hf[tl], pk.v, acc, 0, 0, 0);
        }

        if (cg == 0) {   // lanes 0-15: rows 0-2 = channels, col = pixel
            lds_light[wave][pxl]                   = acc[0] + fmaf(nx, Wl[0], fmaf(ny, Wl[3], nz * Wl[6]));
            lds_light[wave][GROUPS * 16 + pxl]     = acc[1] + fmaf(nx, Wl[1], fmaf(ny, Wl[4], nz * Wl[7]));
            lds_light[wave][GROUPS * 32 + pxl]     = acc[2] + fmaf(nx, Wl[2], fmaf(ny, Wl[5], nz * Wl[8]));
        }
    }
    __syncthreads();   // lights visible

    // ---- Epilogue: coalesced albedo*light (128 floats/channel/wave) ----
    const size_t bbase = (size_t)b * 3 * HW + wavepx0;
    #pragma unroll
    for (int c = 0; c < 3; ++c) {
        const f32x4 av = *(const f32x4*)(albedo + bbase + (size_t)c * HW + lane * 2
                                         - (lane & 1) * 2);   // placeholder avoided
        (void)av;
        break;
    }
    // simple coalesced form: 2 floats per lane per channel (128 px/wave)
    #pragma unroll
    for (int c = 0; c < 3; ++c) {
        const size_t o = bbase + (size_t)c * HW + lane * 2;
        const float2 av = *(const float2*)(albedo + o);
        const float2 lv = *(const float2*)&lds_light[wave][c * GROUPS * 16 + lane * 2];
        float2 ov; ov.x = av.x * lv.x; ov.y = av.y * lv.y;
        *(float2*)(out + o) = ov;
    }
}

extern "C" void kernel_launch(void* const* d_in, const int* in_sizes, int n_in,
                              void* d_out, int out_size, void* d_ws, size_t ws_size,
                              hipStream_t stream)
{
    const float* env    = (const float*)d_in[0];
    const float* normal = (const float*)d_in[1];
    const float* albedo = (const float*)d_in[2];
    float* out          = (float*)d_out;

    const int B = in_sizes[0] / (16 * 32 * 3);               // = 2

    // 512 px per block; grid (512, B) = 1024 blocks = 4 blocks/CU
    dim3 grid(HW / (WAVES * GROUPS * 16), B);
    env_render_fused<<<grid, 256, 0, stream>>>(env, normal, albedo, out);
}